// Round 3
// baseline (110.024 us; speedup 1.0000x reference)
//
#include <hip/hip_runtime.h>

#define N_NODES 1024
#define BATCH   128
#define E_DIM   16

typedef __attribute__((ext_vector_type(8))) short bf16x8;
typedef __attribute__((ext_vector_type(4))) float f32x4;

__device__ __forceinline__ unsigned short f2bf(float f) {
    union { float f; unsigned int u; } v; v.f = f;
    unsigned int u = v.u;
    u += 0x7FFFu + ((u >> 16) & 1u);
    return (unsigned short)(u >> 16);
}

__device__ __forceinline__ void gload_lds16(const void* g, void* l) {
    __builtin_amdgcn_global_load_lds(
        (const __attribute__((address_space(1))) unsigned int*)g,
        (__attribute__((address_space(3))) unsigned int*)l, 16, 0, 0);
}

// ---------------- A: supports = softmax(relu(emb emb^T)) -> bf16 ------------
__global__ __launch_bounds__(256) void k_supports(const float* __restrict__ emb,
                                                  unsigned short* __restrict__ sup) {
    const int n = blockIdx.x;
    const int t = threadIdx.x;
    __shared__ float en[E_DIM];
    __shared__ float red[4];
    if (t < E_DIM) en[t] = emb[n * E_DIM + t];
    __syncthreads();

    float sc[4];
    float mx = -1e30f;
#pragma unroll
    for (int r = 0; r < 4; ++r) {
        const float* em = &emb[(r * 256 + t) * E_DIM];
        float s = 0.f;
#pragma unroll
        for (int e = 0; e < E_DIM; ++e) s = fmaf(en[e], em[e], s);
        s = fmaxf(s, 0.f);
        sc[r] = s;
        mx = fmaxf(mx, s);
    }
#pragma unroll
    for (int o = 32; o > 0; o >>= 1) mx = fmaxf(mx, __shfl_xor(mx, o));
    if ((t & 63) == 0) red[t >> 6] = mx;
    __syncthreads();
    mx = fmaxf(fmaxf(red[0], red[1]), fmaxf(red[2], red[3]));

    float sum = 0.f;
#pragma unroll
    for (int r = 0; r < 4; ++r) { sc[r] = __expf(sc[r] - mx); sum += sc[r]; }
#pragma unroll
    for (int o = 32; o > 0; o >>= 1) sum += __shfl_xor(sum, o);
    __syncthreads();
    if ((t & 63) == 0) red[t >> 6] = sum;
    __syncthreads();
    sum = red[0] + red[1] + red[2] + red[3];
    const float inv = 1.f / sum;
#pragma unroll
    for (int r = 0; r < 4; ++r) sup[n * N_NODES + r * 256 + t] = f2bf(sc[r] * inv);
}

// ---------------- B: xbt[j=b*64+c][m] = bf16(x[b][m][c]) --------------------
__global__ __launch_bounds__(256) void k_xt(const float* __restrict__ x,
                                            unsigned short* __restrict__ xbt) {
    __shared__ __align__(16) unsigned short xt[64 * 72];   // [c][m], pitch 72
    const int t  = threadIdx.x;
    const int b  = blockIdx.y;
    const int m0 = blockIdx.x * 64;
    const int c  = t & 63, mr = t >> 6;
    const float* src = x + ((long)b * N_NODES + m0 + mr) * 64 + c;
#pragma unroll
    for (int i = 0; i < 16; ++i)
        xt[c * 72 + mr + i * 4] = f2bf(src[(long)i * 4 * 64]);
    __syncthreads();
    const int cc = t >> 2, mb = (t & 3) * 16;
    unsigned short* dst = xbt + ((long)b * 64 + cc) * N_NODES + m0 + mb;
    *(bf16x8*)(dst)     = *(const bf16x8*)(&xt[cc * 72 + mb]);
    *(bf16x8*)(dst + 8) = *(const bf16x8*)(&xt[cc * 72 + mb + 8]);
}

// ---------------- C: Wt[n][o][i] bf16 + bias, 4 nodes/block -----------------
__global__ __launch_bounds__(256) void k_weights(const float* __restrict__ emb,
                                                 const float* __restrict__ wpool,
                                                 const float* __restrict__ bpool,
                                                 unsigned short* __restrict__ Wt,
                                                 float* __restrict__ bias) {
    const int t  = threadIdx.x;
    const int n0 = blockIdx.x * 4;
    __shared__ float en[4][E_DIM];
    __shared__ float wl[E_DIM][256];
    __shared__ unsigned short st[4 * 64 * 72];   // [nn][o][i], i-pitch 72
    if (t < 64) en[t >> 4][t & 15] = emb[(n0 + (t >> 4)) * E_DIM + (t & 15)];
    __syncthreads();

    for (int c = 0; c < 16; ++c) {
#pragma unroll
        for (int e = 0; e < E_DIM; ++e) wl[e][t] = wpool[e * 4096 + c * 256 + t];
        __syncthreads();
        const int idx = c * 256 + t;         // = i*64 + o
        const int i = idx >> 6, o = idx & 63;
#pragma unroll
        for (int nn = 0; nn < 4; ++nn) {
            float s = 0.f;
#pragma unroll
            for (int e = 0; e < E_DIM; ++e) s = fmaf(en[nn][e], wl[e][t], s);
            st[nn * 4608 + o * 72 + i] = f2bf(s);
        }
        __syncthreads();
    }
    {   // bias: 4 nodes x 64 o
        const int nn = t >> 6, o = t & 63;
        float s = 0.f;
#pragma unroll
        for (int e = 0; e < E_DIM; ++e) s = fmaf(en[nn][e], bpool[e * 64 + o], s);
        bias[(n0 + nn) * 64 + o] = s;
    }
    // coalesced write-out: 2048 16B granules
#pragma unroll
    for (int r = 0; r < 8; ++r) {
        const int q = r * 256 + t;
        const int nn = q >> 9, rem = q & 511;
        const int o = rem >> 3, ig = (rem & 7) * 8;
        bf16x8 v = *(const bf16x8*)&st[nn * 4608 + o * 72 + ig];
        *(bf16x8*)(Wt + (long)(n0 + nn) * 4096 + o * 64 + ig) = v;
    }
}

// ---------------- D: xg = S @ X  via bf16 MFMA, 128n x 64j tile -------------
// A = S [1024 n][1024 m], B^T = xbt [8192 j][1024 m], C = xg [1024 n][8192 j].
// LDS/buffer: A [4 kblk][128 row][8] (8KB) + B [4 kblk][64 row][8] (4KB).
__global__ __launch_bounds__(256, 4) void k_agg(const unsigned short* __restrict__ S,
                                                const unsigned short* __restrict__ Bt,
                                                unsigned short* __restrict__ xg) {
    __shared__ __align__(16) char lds[24576];
    const int t = threadIdx.x;
    const int lane = t & 63, wid = t >> 6;
    const int n0 = blockIdx.x * 128, j0 = blockIdx.y * 64;
    const int wr = wid >> 1, wc = wid & 1;

    f32x4 acc[4][2];
#pragma unroll
    for (int m = 0; m < 4; ++m)
#pragma unroll
        for (int n = 0; n < 2; ++n) acc[m][n] = f32x4{0.f, 0.f, 0.f, 0.f};

    // 12 x 1KB staging chunks; chunk c = wid*3+i (wave-uniform per issue)
    const unsigned short* sp[3];
    int doff[3];
#pragma unroll
    for (int i = 0; i < 3; ++i) {
        const int c = wid * 3 + i;
        if (c < 8) {   // A half-planes: kblk=c>>1, rows (c&1)*64+lane
            sp[i]   = S + (long)(n0 + (c & 1) * 64 + lane) * 1024 + (c >> 1) * 8;
            doff[i] = c * 1024;
        } else {       // B planes: kblk=c-8, rows lane
            sp[i]   = Bt + (long)(j0 + lane) * 1024 + (c - 8) * 8;
            doff[i] = 8192 + (c - 8) * 1024;
        }
    }
#define STAGE(buf, kt) do {                                      \
        const int ko = (kt) * 32;                                \
        gload_lds16(sp[0] + ko, (buf) + doff[0]);                \
        gload_lds16(sp[1] + ko, (buf) + doff[1]);                \
        gload_lds16(sp[2] + ko, (buf) + doff[2]);                \
    } while (0)

    int aoff[4], boff[2];
#pragma unroll
    for (int m = 0; m < 4; ++m)
        aoff[m] = (lane >> 4) * 2048 + (wr * 64 + m * 16 + (lane & 15)) * 16;
#pragma unroll
    for (int n = 0; n < 2; ++n)
        boff[n] = 8192 + (lane >> 4) * 1024 + (wc * 32 + n * 16 + (lane & 15)) * 16;

    char* cur = lds;
    char* nxt = lds + 12288;
    STAGE(cur, 0);
    __syncthreads();
    for (int kt = 0; kt < 32; ++kt) {
        if (kt + 1 < 32) STAGE(nxt, kt + 1);
        bf16x8 a[4], b[2];
#pragma unroll
        for (int m = 0; m < 4; ++m) a[m] = *(const bf16x8*)(cur + aoff[m]);
#pragma unroll
        for (int n = 0; n < 2; ++n) b[n] = *(const bf16x8*)(cur + boff[n]);
#pragma unroll
        for (int m = 0; m < 4; ++m)
#pragma unroll
            for (int n = 0; n < 2; ++n)
                acc[m][n] = __builtin_amdgcn_mfma_f32_16x16x32_bf16(a[m], b[n], acc[m][n], 0, 0, 0);
        __syncthreads();
        char* tmp = cur; cur = nxt; nxt = tmp;
    }
#undef STAGE

    // epilogue: acc -> LDS bf16 [128 row][64 col] swizzled -> coalesced global
    char* lb = lds;
#pragma unroll
    for (int m = 0; m < 4; ++m) {
        const int row0 = wr * 64 + m * 16 + (lane >> 4) * 4;
#pragma unroll
        for (int n = 0; n < 2; ++n) {
            const int colb = (wc * 32 + n * 16 + (lane & 15)) * 2;
#pragma unroll
            for (int r = 0; r < 4; ++r) {
                const int row = row0 + r;
                *(unsigned short*)(lb + row * 128 + (colb ^ ((row & 7) << 4))) =
                    f2bf(acc[m][n][r]);
            }
        }
    }
    __syncthreads();
#pragma unroll
    for (int i = 0; i < 4; ++i) {
        const int idx = i * 256 + t;          // 1024 granules of 16B
        const int row = idx >> 3, cc = idx & 7;
        bf16x8 v = *(const bf16x8*)(lb + row * 128 + ((cc * 16) ^ ((row & 7) << 4)));
        *(bf16x8*)(xg + (long)(n0 + row) * 8192 + j0 + cc * 8) = v;
    }
}

// ---------------- E: out[b,n,o] = xg_n[b,:] @ W_n + bias_n ------------------
__global__ __launch_bounds__(256) void k_out(const unsigned short* __restrict__ xg,
                                             const unsigned short* __restrict__ Wt,
                                             const float* __restrict__ bias,
                                             float* __restrict__ out) {
    __shared__ __align__(16) char lds[32768];   // in: xg 16KB | Wt 8KB ; out: 32KB f32
    const int t = threadIdx.x, lane = t & 63, wid = t >> 6;
    const int node = blockIdx.x;
    const unsigned short* gx = xg + (long)node * 8192;
    const unsigned short* gw = Wt + (long)node * 4096;
#pragma unroll
    for (int i = 0; i < 4; ++i) {
        const int c = wid * 4 + i;            // 0..15
        const int kblk = c >> 1, bh = c & 1;
        gload_lds16(gx + (bh * 64 + lane) * 64 + kblk * 8, lds + c * 1024);
    }
#pragma unroll
    for (int i = 0; i < 2; ++i) {
        const int c = wid * 2 + i;            // 0..7
        gload_lds16(gw + lane * 64 + c * 8, lds + 16384 + c * 1024);
    }
    __syncthreads();

    f32x4 acc[2][4];
#pragma unroll
    for (int m = 0; m < 2; ++m)
#pragma unroll
        for (int n = 0; n < 4; ++n) acc[m][n] = f32x4{0.f, 0.f, 0.f, 0.f};

#pragma unroll
    for (int s = 0; s < 2; ++s) {
        const int kb = s * 4 + (lane >> 4);
        bf16x8 a[2], b[4];
#pragma unroll
        for (int m = 0; m < 2; ++m)
            a[m] = *(const bf16x8*)(lds + kb * 2048 + (wid * 32 + m * 16 + (lane & 15)) * 16);
#pragma unroll
        for (int n = 0; n < 4; ++n)
            b[n] = *(const bf16x8*)(lds + 16384 + kb * 1024 + (n * 16 + (lane & 15)) * 16);
#pragma unroll
        for (int m = 0; m < 2; ++m)
#pragma unroll
            for (int n = 0; n < 4; ++n)
                acc[m][n] = __builtin_amdgcn_mfma_f32_16x16x32_bf16(a[m], b[n], acc[m][n], 0, 0, 0);
    }
    __syncthreads();   // done reading input LDS; reuse as f32 output staging

    // stage (acc + bias) into swizzled f32 [128 b][64 o]
#pragma unroll
    for (int n = 0; n < 4; ++n) {
        const int o = n * 16 + (lane & 15);
        const float bv = bias[node * 64 + o];
#pragma unroll
        for (int m = 0; m < 2; ++m) {
            const int row0 = wid * 32 + m * 16 + (lane >> 4) * 4;
#pragma unroll
            for (int r = 0; r < 4; ++r) {
                const int row = row0 + r;
                *(float*)(lds + row * 256 + ((o * 4) ^ ((row & 7) << 4))) =
                    acc[m][n][r] + bv;
            }
        }
    }
    __syncthreads();
    // coalesced dwordx4 stores: row b = 256B contiguous in out[b][node][:]
#pragma unroll
    for (int i = 0; i < 8; ++i) {
        const int idx = i * 256 + t;          // 2048 granules of 16B
        const int row = idx >> 4, cc = idx & 15;
        f32x4 v = *(const f32x4*)(lds + row * 256 + ((cc * 16) ^ ((row & 7) << 4)));
        *(f32x4*)(out + (long)row * 65536 + node * 64 + cc * 4) = v;
    }
}

extern "C" void kernel_launch(void* const* d_in, const int* in_sizes, int n_in,
                              void* d_out, int out_size, void* d_ws, size_t ws_size,
                              hipStream_t stream) {
    const float* x     = (const float*)d_in[0];
    const float* emb   = (const float*)d_in[1];
    const float* wpool = (const float*)d_in[2];
    const float* bpool = (const float*)d_in[3];
    float* out = (float*)d_out;

    char* ws = (char*)d_ws;
    unsigned short* sup  = (unsigned short*)(ws);                        // 2 MiB
    unsigned short* xbt  = (unsigned short*)(ws + (2u  << 20));          // 16 MiB
    unsigned short* Wt   = (unsigned short*)(ws + (18u << 20));          // 8 MiB
    float*          bias = (float*)         (ws + (26u << 20));          // 256 KiB
    unsigned short* xg   = (unsigned short*)(ws + (27u << 20));          // 16 MiB
    (void)in_sizes; (void)n_in; (void)out_size; (void)ws_size;

    k_supports<<<dim3(N_NODES), dim3(256), 0, stream>>>(emb, sup);
    k_xt<<<dim3(16, BATCH), dim3(256), 0, stream>>>(x, xbt);
    k_weights<<<dim3(256), dim3(256), 0, stream>>>(emb, wpool, bpool, Wt, bias);
    k_agg<<<dim3(8, 128), dim3(256), 0, stream>>>(sup, xbt, xg);
    k_out<<<dim3(N_NODES), dim3(256), 0, stream>>>(xg, Wt, bias, out);
}

// Round 4
// 88.662 us; speedup vs baseline: 1.2409x; 1.2409x over previous
//
#include <hip/hip_runtime.h>

#define N_NODES 1024
#define BATCH   128
#define E_DIM   16

typedef __attribute__((ext_vector_type(8))) short bf16x8;
typedef __attribute__((ext_vector_type(4))) float f32x4;
typedef __attribute__((ext_vector_type(16))) float f32x16;

__device__ __forceinline__ unsigned short f2bf(float f) {
    union { float f; unsigned int u; } v; v.f = f;
    unsigned int u = v.u;
    u += 0x7FFFu + ((u >> 16) & 1u);
    return (unsigned short)(u >> 16);
}

__device__ __forceinline__ void gload_lds16(const void* g, void* l) {
    __builtin_amdgcn_global_load_lds(
        (const __attribute__((address_space(1))) unsigned int*)g,
        (__attribute__((address_space(3))) unsigned int*)l, 16, 0, 0);
}

// ---------------- A: supports = softmax(relu(emb emb^T)) -> bf16 ------------
__global__ __launch_bounds__(256) void k_supports(const float* __restrict__ emb,
                                                  unsigned short* __restrict__ sup) {
    const int n = blockIdx.x;
    const int t = threadIdx.x;
    __shared__ float en[E_DIM];
    __shared__ float red[4];
    if (t < E_DIM) en[t] = emb[n * E_DIM + t];
    __syncthreads();

    float sc[4];
    float mx = -1e30f;
#pragma unroll
    for (int r = 0; r < 4; ++r) {
        const float* em = &emb[(r * 256 + t) * E_DIM];
        float s = 0.f;
#pragma unroll
        for (int e = 0; e < E_DIM; ++e) s = fmaf(en[e], em[e], s);
        s = fmaxf(s, 0.f);
        sc[r] = s;
        mx = fmaxf(mx, s);
    }
#pragma unroll
    for (int o = 32; o > 0; o >>= 1) mx = fmaxf(mx, __shfl_xor(mx, o));
    if ((t & 63) == 0) red[t >> 6] = mx;
    __syncthreads();
    mx = fmaxf(fmaxf(red[0], red[1]), fmaxf(red[2], red[3]));

    float sum = 0.f;
#pragma unroll
    for (int r = 0; r < 4; ++r) { sc[r] = __expf(sc[r] - mx); sum += sc[r]; }
#pragma unroll
    for (int o = 32; o > 0; o >>= 1) sum += __shfl_xor(sum, o);
    __syncthreads();
    if ((t & 63) == 0) red[t >> 6] = sum;
    __syncthreads();
    sum = red[0] + red[1] + red[2] + red[3];
    const float inv = 1.f / sum;
#pragma unroll
    for (int r = 0; r < 4; ++r) sup[n * N_NODES + r * 256 + t] = f2bf(sc[r] * inv);
}

// ---------------- B: xbt[j=b*64+c][m] = bf16(x[b][m][c]) --------------------
__global__ __launch_bounds__(256) void k_xt(const float* __restrict__ x,
                                            unsigned short* __restrict__ xbt) {
    __shared__ __align__(16) unsigned short xt[64 * 72];   // [c][m], pitch 72
    const int t  = threadIdx.x;
    const int b  = blockIdx.y;
    const int m0 = blockIdx.x * 64;
    const int c  = t & 63, mr = t >> 6;
    const float* src = x + ((long)b * N_NODES + m0 + mr) * 64 + c;
#pragma unroll
    for (int i = 0; i < 16; ++i)
        xt[c * 72 + mr + i * 4] = f2bf(src[(long)i * 4 * 64]);
    __syncthreads();
    const int cc = t >> 2, mb = (t & 3) * 16;
    unsigned short* dst = xbt + ((long)b * 64 + cc) * N_NODES + m0 + mb;
    *(bf16x8*)(dst)     = *(const bf16x8*)(&xt[cc * 72 + mb]);
    *(bf16x8*)(dst + 8) = *(const bf16x8*)(&xt[cc * 72 + mb + 8]);
}

// ---------------- C: Wt[n][o][i] bf16, bias[n][o] f32 (R2 version) ----------
__global__ __launch_bounds__(256) void k_weights(const float* __restrict__ emb,
                                                 const float* __restrict__ wpool,
                                                 const float* __restrict__ bpool,
                                                 unsigned short* __restrict__ Wt,
                                                 float* __restrict__ bias) {
    const int n = blockIdx.x;
    const int t = threadIdx.x;
    __shared__ float en[E_DIM];
    __shared__ float wl[64 * 65];   // [i][o], pitch 65
    if (t < E_DIM) en[t] = emb[n * E_DIM + t];
    __syncthreads();
#pragma unroll 4
    for (int r = 0; r < 16; ++r) {
        const int idx = r * 256 + t;    // i = idx>>6, o = idx&63
        float s = 0.f;
#pragma unroll
        for (int e = 0; e < E_DIM; ++e) s = fmaf(en[e], wpool[e * 4096 + idx], s);
        wl[(idx >> 6) * 65 + (idx & 63)] = s;
    }
    if (t < 64) {
        float s = 0.f;
#pragma unroll
        for (int e = 0; e < E_DIM; ++e) s = fmaf(en[e], bpool[e * 64 + t], s);
        bias[n * 64 + t] = s;
    }
    __syncthreads();
#pragma unroll 4
    for (int r = 0; r < 16; ++r) {
        const int idx = r * 256 + t;    // o = idx>>6, i = idx&63
        Wt[(long)n * 4096 + idx] = f2bf(wl[(idx & 63) * 65 + (idx >> 6)]);
    }
}

// ---------------- D: xg = S @ X, 128x128 tile, BK=64, 32x32x16 MFMA ---------
// A = S [1024 n][1024 m], B^T = xbt [8192 j][1024 m], C = xg [1024 n][8192 j].
// LDS per buffer: A [8 kblk][128 row][8] = 16KB + B same = 16KB; dbuf 64KB.
__global__ __launch_bounds__(256, 2) void k_agg(const unsigned short* __restrict__ S,
                                                const unsigned short* __restrict__ Bt,
                                                unsigned short* __restrict__ xg) {
    __shared__ __align__(16) char lds[65536];
    const int t = threadIdx.x;
    const int lane = t & 63, wid = t >> 6;

    // bijective XCD swizzle: 512 blocks, 8 XCDs, 64 blocks per XCD chunk
    const int hw   = blockIdx.x + 8 * blockIdx.y;      // grid (8, 64)
    const int work = (hw & 7) * 64 + (hw >> 3);
    const int n0 = (work & 7) * 128, j0 = (work >> 3) * 128;
    const int wr = wid >> 1, wc = wid & 1;

    f32x16 acc[2][2];
#pragma unroll
    for (int m = 0; m < 2; ++m)
#pragma unroll
        for (int n = 0; n < 2; ++n)
#pragma unroll
            for (int r = 0; r < 16; ++r) acc[m][n][r] = 0.f;

    // 32 staging chunks of 1KB; wave handles c = wid*8 .. wid*8+7
    const unsigned short* sp[8];
    int doff[8];
#pragma unroll
    for (int i = 0; i < 8; ++i) {
        const int c = wid * 8 + i;
        if (c < 16) {          // A: kblk=c>>1, rows (c&1)*64+lane
            sp[i]   = S + (long)(n0 + (c & 1) * 64 + lane) * 1024 + (c >> 1) * 8;
            doff[i] = c * 1024;
        } else {               // B: cc=c-16
            const int cc = c - 16;
            sp[i]   = Bt + (long)(j0 + (cc & 1) * 64 + lane) * 1024 + (cc >> 1) * 8;
            doff[i] = 16384 + cc * 1024;
        }
    }
#define STAGE(buf, kt) do {                                       \
        const int ko = (kt) * 64;                                 \
        gload_lds16(sp[0] + ko, (buf) + doff[0]);                 \
        gload_lds16(sp[1] + ko, (buf) + doff[1]);                 \
        gload_lds16(sp[2] + ko, (buf) + doff[2]);                 \
        gload_lds16(sp[3] + ko, (buf) + doff[3]);                 \
        gload_lds16(sp[4] + ko, (buf) + doff[4]);                 \
        gload_lds16(sp[5] + ko, (buf) + doff[5]);                 \
        gload_lds16(sp[6] + ko, (buf) + doff[6]);                 \
        gload_lds16(sp[7] + ko, (buf) + doff[7]);                 \
    } while (0)

    // fragment offsets: kstep s gives kblk = s*2 + (lane>>5)
    int aoff[2], boff[2];
#pragma unroll
    for (int m = 0; m < 2; ++m)
        aoff[m] = (lane >> 5) * 2048 + (wr * 64 + m * 32 + (lane & 31)) * 16;
#pragma unroll
    for (int n = 0; n < 2; ++n)
        boff[n] = 16384 + (lane >> 5) * 2048 + (wc * 64 + n * 32 + (lane & 31)) * 16;

    char* cur = lds;
    char* nxt = lds + 32768;
    STAGE(cur, 0);
    __syncthreads();
    for (int kt = 0; kt < 16; ++kt) {
        if (kt + 1 < 16) STAGE(nxt, kt + 1);
#pragma unroll
        for (int s = 0; s < 4; ++s) {
            bf16x8 a[2], b[2];
#pragma unroll
            for (int m = 0; m < 2; ++m) a[m] = *(const bf16x8*)(cur + s * 4096 + aoff[m]);
#pragma unroll
            for (int n = 0; n < 2; ++n) b[n] = *(const bf16x8*)(cur + s * 4096 + boff[n]);
#pragma unroll
            for (int m = 0; m < 2; ++m)
#pragma unroll
                for (int n = 0; n < 2; ++n)
                    acc[m][n] = __builtin_amdgcn_mfma_f32_32x32x16_bf16(a[m], b[n], acc[m][n], 0, 0, 0);
        }
        __syncthreads();
        char* tmp = cur; cur = nxt; nxt = tmp;
    }
#undef STAGE

    // epilogue: acc -> LDS bf16 [128 row][128 col] swizzled -> coalesced out
    // C layout (32x32): col = lane&31, row = (r&3) + 8*(r>>2) + 4*(lane>>5)
    char* lb = lds;
#pragma unroll
    for (int m = 0; m < 2; ++m) {
#pragma unroll
        for (int n = 0; n < 2; ++n) {
            const int col  = wc * 64 + n * 32 + (lane & 31);
            const int rowb = wr * 64 + m * 32 + 4 * (lane >> 5);
#pragma unroll
            for (int r = 0; r < 16; ++r) {
                const int row = rowb + (r & 3) + 8 * (r >> 2);
                *(unsigned short*)(lb + row * 256 + ((col * 2) ^ ((row & 7) << 4))) =
                    f2bf(acc[m][n][r]);
            }
        }
    }
    __syncthreads();
#pragma unroll
    for (int i = 0; i < 8; ++i) {
        const int idx = i * 256 + t;          // 2048 granules of 16B
        const int row = idx >> 4, cc = idx & 15;
        bf16x8 v = *(const bf16x8*)(lb + row * 256 + ((cc * 16) ^ ((row & 7) << 4)));
        *(bf16x8*)(xg + (long)(n0 + row) * 8192 + j0 + cc * 8) = v;
    }
}

// ---------------- E: out[b,n,o] = xg_n[b,:] @ W_n + bias_n (R2 version) -----
__global__ __launch_bounds__(256) void k_out(const unsigned short* __restrict__ xg,
                                             const unsigned short* __restrict__ Wt,
                                             const float* __restrict__ bias,
                                             float* __restrict__ out) {
    __shared__ __align__(16) char lds[24576];   // xg_n 16KB (8 planes) | Wt_n 8KB
    const int t = threadIdx.x, lane = t & 63, wid = t >> 6;
    const int node = blockIdx.x;
    const unsigned short* gx = xg + (long)node * 8192;
    const unsigned short* gw = Wt + (long)node * 4096;
#pragma unroll
    for (int i = 0; i < 4; ++i) {
        const int c = wid * 4 + i;            // 0..15
        const int kblk = c >> 1, bh = c & 1;
        gload_lds16(gx + (bh * 64 + lane) * 64 + kblk * 8, lds + c * 1024);
    }
#pragma unroll
    for (int i = 0; i < 2; ++i) {
        const int c = wid * 2 + i;            // 0..7
        gload_lds16(gw + lane * 64 + c * 8, lds + 16384 + c * 1024);
    }
    __syncthreads();

    f32x4 acc[2][4];
#pragma unroll
    for (int m = 0; m < 2; ++m)
#pragma unroll
        for (int n = 0; n < 4; ++n) acc[m][n] = f32x4{0.f, 0.f, 0.f, 0.f};

#pragma unroll
    for (int s = 0; s < 2; ++s) {
        const int kb = s * 4 + (lane >> 4);
        bf16x8 a[2], b[4];
#pragma unroll
        for (int m = 0; m < 2; ++m)
            a[m] = *(const bf16x8*)(lds + kb * 2048 + (wid * 32 + m * 16 + (lane & 15)) * 16);
#pragma unroll
        for (int n = 0; n < 4; ++n)
            b[n] = *(const bf16x8*)(lds + 16384 + kb * 1024 + (n * 16 + (lane & 15)) * 16);
#pragma unroll
        for (int m = 0; m < 2; ++m)
#pragma unroll
            for (int n = 0; n < 4; ++n)
                acc[m][n] = __builtin_amdgcn_mfma_f32_16x16x32_bf16(a[m], b[n], acc[m][n], 0, 0, 0);
    }

#pragma unroll
    for (int n = 0; n < 4; ++n) {
        const int o = n * 16 + (lane & 15);
        const float bv = bias[node * 64 + o];
#pragma unroll
        for (int m = 0; m < 2; ++m) {
            const int b0 = wid * 32 + m * 16 + (lane >> 4) * 4;
#pragma unroll
            for (int r = 0; r < 4; ++r)
                out[(long)(b0 + r) * 65536 + node * 64 + o] = acc[m][n][r] + bv;
        }
    }
}

extern "C" void kernel_launch(void* const* d_in, const int* in_sizes, int n_in,
                              void* d_out, int out_size, void* d_ws, size_t ws_size,
                              hipStream_t stream) {
    const float* x     = (const float*)d_in[0];
    const float* emb   = (const float*)d_in[1];
    const float* wpool = (const float*)d_in[2];
    const float* bpool = (const float*)d_in[3];
    float* out = (float*)d_out;

    char* ws = (char*)d_ws;
    unsigned short* sup  = (unsigned short*)(ws);                        // 2 MiB
    unsigned short* xbt  = (unsigned short*)(ws + (2u  << 20));          // 16 MiB
    unsigned short* Wt   = (unsigned short*)(ws + (18u << 20));          // 8 MiB
    float*          bias = (float*)         (ws + (26u << 20));          // 256 KiB
    unsigned short* xg   = (unsigned short*)(ws + (27u << 20));          // 16 MiB
    (void)in_sizes; (void)n_in; (void)out_size; (void)ws_size;

    k_supports<<<dim3(N_NODES), dim3(256), 0, stream>>>(emb, sup);
    k_xt<<<dim3(16, BATCH), dim3(256), 0, stream>>>(x, xbt);
    k_weights<<<dim3(N_NODES), dim3(256), 0, stream>>>(emb, wpool, bpool, Wt, bias);
    k_agg<<<dim3(8, 64), dim3(256), 0, stream>>>(sup, xbt, xg);
    k_out<<<dim3(N_NODES), dim3(256), 0, stream>>>(xg, Wt, bias, out);
}

// Round 5
// 85.960 us; speedup vs baseline: 1.2800x; 1.0314x over previous
//
#include <hip/hip_runtime.h>

#define N_NODES 1024
#define BATCH   128
#define E_DIM   16

typedef __attribute__((ext_vector_type(8))) short bf16x8;
typedef __attribute__((ext_vector_type(4))) float f32x4;
typedef __attribute__((ext_vector_type(16))) float f32x16;

__device__ __forceinline__ unsigned short f2bf(float f) {
    union { float f; unsigned int u; } v; v.f = f;
    unsigned int u = v.u;
    u += 0x7FFFu + ((u >> 16) & 1u);
    return (unsigned short)(u >> 16);
}

__device__ __forceinline__ void gload_lds16(const void* g, void* l) {
    __builtin_amdgcn_global_load_lds(
        (const __attribute__((address_space(1))) unsigned int*)g,
        (__attribute__((address_space(3))) unsigned int*)l, 16, 0, 0);
}

// ---------------- A: supports = softmax(relu(emb emb^T)) -> bf16 ------------
__global__ __launch_bounds__(256) void k_supports(const float* __restrict__ emb,
                                                  unsigned short* __restrict__ sup) {
    const int n = blockIdx.x;
    const int t = threadIdx.x;
    __shared__ float en[E_DIM];
    __shared__ float red[4];
    if (t < E_DIM) en[t] = emb[n * E_DIM + t];
    __syncthreads();

    float sc[4];
    float mx = -1e30f;
#pragma unroll
    for (int r = 0; r < 4; ++r) {
        const float* em = &emb[(r * 256 + t) * E_DIM];
        float s = 0.f;
#pragma unroll
        for (int e = 0; e < E_DIM; ++e) s = fmaf(en[e], em[e], s);
        s = fmaxf(s, 0.f);
        sc[r] = s;
        mx = fmaxf(mx, s);
    }
#pragma unroll
    for (int o = 32; o > 0; o >>= 1) mx = fmaxf(mx, __shfl_xor(mx, o));
    if ((t & 63) == 0) red[t >> 6] = mx;
    __syncthreads();
    mx = fmaxf(fmaxf(red[0], red[1]), fmaxf(red[2], red[3]));

    float sum = 0.f;
#pragma unroll
    for (int r = 0; r < 4; ++r) { sc[r] = __expf(sc[r] - mx); sum += sc[r]; }
#pragma unroll
    for (int o = 32; o > 0; o >>= 1) sum += __shfl_xor(sum, o);
    __syncthreads();
    if ((t & 63) == 0) red[t >> 6] = sum;
    __syncthreads();
    sum = red[0] + red[1] + red[2] + red[3];
    const float inv = 1.f / sum;
#pragma unroll
    for (int r = 0; r < 4; ++r) sup[n * N_NODES + r * 256 + t] = f2bf(sc[r] * inv);
}

// ---------------- B: xbt[j=b*64+c][m] = bf16(x[b][m][c]) --------------------
__global__ __launch_bounds__(256) void k_xt(const float* __restrict__ x,
                                            unsigned short* __restrict__ xbt) {
    __shared__ __align__(16) unsigned short xt[64 * 72];   // [c][m], pitch 72
    const int t  = threadIdx.x;
    const int b  = blockIdx.y;
    const int m0 = blockIdx.x * 64;
    const int c  = t & 63, mr = t >> 6;
    const float* src = x + ((long)b * N_NODES + m0 + mr) * 64 + c;
#pragma unroll
    for (int i = 0; i < 16; ++i)
        xt[c * 72 + mr + i * 4] = f2bf(src[(long)i * 4 * 64]);
    __syncthreads();
    const int cc = t >> 2, mb = (t & 3) * 16;
    unsigned short* dst = xbt + ((long)b * 64 + cc) * N_NODES + m0 + mb;
    *(bf16x8*)(dst)     = *(const bf16x8*)(&xt[cc * 72 + mb]);
    *(bf16x8*)(dst + 8) = *(const bf16x8*)(&xt[cc * 72 + mb + 8]);
}

// ---------------- C: Wt[n][o][i] bf16, bias[n][o] f32 -----------------------
__global__ __launch_bounds__(256) void k_weights(const float* __restrict__ emb,
                                                 const float* __restrict__ wpool,
                                                 const float* __restrict__ bpool,
                                                 unsigned short* __restrict__ Wt,
                                                 float* __restrict__ bias) {
    const int n = blockIdx.x;
    const int t = threadIdx.x;
    __shared__ float en[E_DIM];
    __shared__ float wl[64 * 65];   // [i][o], pitch 65
    if (t < E_DIM) en[t] = emb[n * E_DIM + t];
    __syncthreads();
#pragma unroll 4
    for (int r = 0; r < 16; ++r) {
        const int idx = r * 256 + t;    // i = idx>>6, o = idx&63
        float s = 0.f;
#pragma unroll
        for (int e = 0; e < E_DIM; ++e) s = fmaf(en[e], wpool[e * 4096 + idx], s);
        wl[(idx >> 6) * 65 + (idx & 63)] = s;
    }
    if (t < 64) {
        float s = 0.f;
#pragma unroll
        for (int e = 0; e < E_DIM; ++e) s = fmaf(en[e], bpool[e * 64 + t], s);
        bias[n * 64 + t] = s;
    }
    __syncthreads();
#pragma unroll 4
    for (int r = 0; r < 16; ++r) {
        const int idx = r * 256 + t;    // o = idx>>6, i = idx&63
        Wt[(long)n * 4096 + idx] = f2bf(wl[(idx & 63) * 65 + (idx >> 6)]);
    }
}

// ---------------- D: xg = S @ X, 128x128, BK=64, counted-vmcnt pipeline -----
// A = S [1024 n][1024 m], B^T = xbt [8192 j][1024 m], C = xg [1024 n][8192 j].
// LDS per buffer: A [8 kblk][128 row][8] = 16KB + B same = 16KB; dbuf 64KB.
__global__ __launch_bounds__(256, 2) void k_agg(const unsigned short* __restrict__ S,
                                                const unsigned short* __restrict__ Bt,
                                                unsigned short* __restrict__ xg) {
    __shared__ __align__(16) char lds[65536];
    const int t = threadIdx.x;
    const int lane = t & 63, wid = t >> 6;

    // bijective XCD swizzle: 512 blocks, 8 XCDs, 64 blocks per XCD chunk
    const int hw   = blockIdx.x + 8 * blockIdx.y;      // grid (8, 64)
    const int work = (hw & 7) * 64 + (hw >> 3);
    const int n0 = (work & 7) * 128, j0 = (work >> 3) * 128;
    const int wr = wid >> 1, wc = wid & 1;

    f32x16 acc[2][2];
#pragma unroll
    for (int m = 0; m < 2; ++m)
#pragma unroll
        for (int n = 0; n < 2; ++n)
#pragma unroll
            for (int r = 0; r < 16; ++r) acc[m][n][r] = 0.f;

    // 32 staging chunks of 1KB; wave handles c = wid*8 .. wid*8+7
    const unsigned short* sp[8];
    int doff[8];
#pragma unroll
    for (int i = 0; i < 8; ++i) {
        const int c = wid * 8 + i;
        if (c < 16) {          // A: kblk=c>>1, rows (c&1)*64+lane
            sp[i]   = S + (long)(n0 + (c & 1) * 64 + lane) * 1024 + (c >> 1) * 8;
            doff[i] = c * 1024;
        } else {               // B: cc=c-16
            const int cc = c - 16;
            sp[i]   = Bt + (long)(j0 + (cc & 1) * 64 + lane) * 1024 + (cc >> 1) * 8;
            doff[i] = 16384 + cc * 1024;
        }
    }
#define STAGE(buf, kt) do {                                       \
        const int ko = (kt) * 64;                                 \
        gload_lds16(sp[0] + ko, (buf) + doff[0]);                 \
        gload_lds16(sp[1] + ko, (buf) + doff[1]);                 \
        gload_lds16(sp[2] + ko, (buf) + doff[2]);                 \
        gload_lds16(sp[3] + ko, (buf) + doff[3]);                 \
        gload_lds16(sp[4] + ko, (buf) + doff[4]);                 \
        gload_lds16(sp[5] + ko, (buf) + doff[5]);                 \
        gload_lds16(sp[6] + ko, (buf) + doff[6]);                 \
        gload_lds16(sp[7] + ko, (buf) + doff[7]);                 \
    } while (0)

    // fragment offsets: kstep s gives kblk = s*2 + (lane>>5)
    int aoff[2], boff[2];
#pragma unroll
    for (int m = 0; m < 2; ++m)
        aoff[m] = (lane >> 5) * 2048 + (wr * 64 + m * 32 + (lane & 31)) * 16;
#pragma unroll
    for (int n = 0; n < 2; ++n)
        boff[n] = 16384 + (lane >> 5) * 2048 + (wc * 64 + n * 32 + (lane & 31)) * 16;

    char* cur = lds;
    char* nxt = lds + 32768;
    STAGE(cur, 0);
    for (int kt = 0; kt < 16; ++kt) {
        if (kt + 1 < 16) {
            STAGE(nxt, kt + 1);
            // wait only for kt's 8 loads; kt+1's 8 stay in flight across barrier
            asm volatile("s_waitcnt vmcnt(8)" ::: "memory");
        } else {
            asm volatile("s_waitcnt vmcnt(0)" ::: "memory");
        }
        __builtin_amdgcn_s_barrier();
        __builtin_amdgcn_sched_barrier(0);   // no LDS reads may hoist above
        __builtin_amdgcn_s_setprio(1);
#pragma unroll
        for (int s = 0; s < 4; ++s) {
            bf16x8 a[2], b[2];
#pragma unroll
            for (int m = 0; m < 2; ++m) a[m] = *(const bf16x8*)(cur + s * 4096 + aoff[m]);
#pragma unroll
            for (int n = 0; n < 2; ++n) b[n] = *(const bf16x8*)(cur + s * 4096 + boff[n]);
#pragma unroll
            for (int m = 0; m < 2; ++m)
#pragma unroll
                for (int n = 0; n < 2; ++n)
                    acc[m][n] = __builtin_amdgcn_mfma_f32_32x32x16_bf16(a[m], b[n], acc[m][n], 0, 0, 0);
        }
        __builtin_amdgcn_s_setprio(0);
        __builtin_amdgcn_sched_barrier(0);   // all LDS reads issued+consumed above
        __builtin_amdgcn_s_barrier();        // readers done before next STAGE overwrites
        __builtin_amdgcn_sched_barrier(0);
        char* tmp = cur; cur = nxt; nxt = tmp;
    }
#undef STAGE

    // epilogue: acc -> LDS bf16 [128 row][128 col] swizzled -> coalesced out
    // C layout (32x32): col = lane&31, row = (r&3) + 8*(r>>2) + 4*(lane>>5)
    char* lb = lds;
#pragma unroll
    for (int m = 0; m < 2; ++m) {
#pragma unroll
        for (int n = 0; n < 2; ++n) {
            const int col  = wc * 64 + n * 32 + (lane & 31);
            const int rowb = wr * 64 + m * 32 + 4 * (lane >> 5);
#pragma unroll
            for (int r = 0; r < 16; ++r) {
                const int row = rowb + (r & 3) + 8 * (r >> 2);
                *(unsigned short*)(lb + row * 256 + ((col * 2) ^ ((row & 7) << 4))) =
                    f2bf(acc[m][n][r]);
            }
        }
    }
    __syncthreads();
#pragma unroll
    for (int i = 0; i < 8; ++i) {
        const int idx = i * 256 + t;          // 2048 granules of 16B
        const int row = idx >> 4, cc = idx & 15;
        bf16x8 v = *(const bf16x8*)(lb + row * 256 + ((cc * 16) ^ ((row & 7) << 4)));
        *(bf16x8*)(xg + (long)(n0 + row) * 8192 + j0 + cc * 8) = v;
    }
}

// ---------------- E: out[b,n,o] = xg_n[b,:] @ W_n + bias_n ------------------
__global__ __launch_bounds__(256) void k_out(const unsigned short* __restrict__ xg,
                                             const unsigned short* __restrict__ Wt,
                                             const float* __restrict__ bias,
                                             float* __restrict__ out) {
    __shared__ __align__(16) char lds[24576];   // xg_n 16KB (8 planes) | Wt_n 8KB
    const int t = threadIdx.x, lane = t & 63, wid = t >> 6;
    const int node = blockIdx.x;
    const unsigned short* gx = xg + (long)node * 8192;
    const unsigned short* gw = Wt + (long)node * 4096;
#pragma unroll
    for (int i = 0; i < 4; ++i) {
        const int c = wid * 4 + i;            // 0..15
        const int kblk = c >> 1, bh = c & 1;
        gload_lds16(gx + (bh * 64 + lane) * 64 + kblk * 8, lds + c * 1024);
    }
#pragma unroll
    for (int i = 0; i < 2; ++i) {
        const int c = wid * 2 + i;            // 0..7
        gload_lds16(gw + lane * 64 + c * 8, lds + 16384 + c * 1024);
    }
    __syncthreads();

    f32x4 acc[2][4];
#pragma unroll
    for (int m = 0; m < 2; ++m)
#pragma unroll
        for (int n = 0; n < 4; ++n) acc[m][n] = f32x4{0.f, 0.f, 0.f, 0.f};

#pragma unroll
    for (int s = 0; s < 2; ++s) {
        const int kb = s * 4 + (lane >> 4);
        bf16x8 a[2], b[4];
#pragma unroll
        for (int m = 0; m < 2; ++m)
            a[m] = *(const bf16x8*)(lds + kb * 2048 + (wid * 32 + m * 16 + (lane & 15)) * 16);
#pragma unroll
        for (int n = 0; n < 4; ++n)
            b[n] = *(const bf16x8*)(lds + 16384 + kb * 1024 + (n * 16 + (lane & 15)) * 16);
#pragma unroll
        for (int m = 0; m < 2; ++m)
#pragma unroll
            for (int n = 0; n < 4; ++n)
                acc[m][n] = __builtin_amdgcn_mfma_f32_16x16x32_bf16(a[m], b[n], acc[m][n], 0, 0, 0);
    }

#pragma unroll
    for (int n = 0; n < 4; ++n) {
        const int o = n * 16 + (lane & 15);
        const float bv = bias[node * 64 + o];
#pragma unroll
        for (int m = 0; m < 2; ++m) {
            const int b0 = wid * 32 + m * 16 + (lane >> 4) * 4;
#pragma unroll
            for (int r = 0; r < 4; ++r)
                out[(long)(b0 + r) * 65536 + node * 64 + o] = acc[m][n][r] + bv;
        }
    }
}

extern "C" void kernel_launch(void* const* d_in, const int* in_sizes, int n_in,
                              void* d_out, int out_size, void* d_ws, size_t ws_size,
                              hipStream_t stream) {
    const float* x     = (const float*)d_in[0];
    const float* emb   = (const float*)d_in[1];
    const float* wpool = (const float*)d_in[2];
    const float* bpool = (const float*)d_in[3];
    float* out = (float*)d_out;

    char* ws = (char*)d_ws;
    unsigned short* sup  = (unsigned short*)(ws);                        // 2 MiB
    unsigned short* xbt  = (unsigned short*)(ws + (2u  << 20));          // 16 MiB
    unsigned short* Wt   = (unsigned short*)(ws + (18u << 20));          // 8 MiB
    float*          bias = (float*)         (ws + (26u << 20));          // 256 KiB
    unsigned short* xg   = (unsigned short*)(ws + (27u << 20));          // 16 MiB
    (void)in_sizes; (void)n_in; (void)out_size; (void)ws_size;

    k_supports<<<dim3(N_NODES), dim3(256), 0, stream>>>(emb, sup);
    k_xt<<<dim3(16, BATCH), dim3(256), 0, stream>>>(x, xbt);
    k_weights<<<dim3(N_NODES), dim3(256), 0, stream>>>(emb, wpool, bpool, Wt, bias);
    k_agg<<<dim3(8, 64), dim3(256), 0, stream>>>(sup, xbt, xg);
    k_out<<<dim3(N_NODES), dim3(256), 0, stream>>>(xg, Wt, bias, out);
}

// Round 6
// 70.891 us; speedup vs baseline: 1.5520x; 1.2126x over previous
//
#include <hip/hip_runtime.h>

#define N_NODES 1024
#define BATCH   128
#define E_DIM   16

// Operand panel format (bf16, per 128-row x 1024-k panel, 256KB):
//   elem(row, k) at  (k>>6)*8192 + ((k>>3)&7)*1024 + row*8 + (k&7)
// i.e. [kt 16][kblk 8][row 128][8 elems]; one kt slab (16KB) is staged per
// K-iteration as 16 contiguous 1KB chunks -> perfectly coalesced
// global_load_lds, LDS layout [kblk][row][8] (conflict-free b128 reads).

typedef __attribute__((ext_vector_type(8))) short bf16x8;
typedef __attribute__((ext_vector_type(4))) float f32x4;
typedef __attribute__((ext_vector_type(16))) float f32x16;

__device__ __forceinline__ unsigned short f2bf(float f) {
    union { float f; unsigned int u; } v; v.f = f;
    unsigned int u = v.u;
    u += 0x7FFFu + ((u >> 16) & 1u);
    return (unsigned short)(u >> 16);
}

__device__ __forceinline__ void gload_lds16(const void* g, void* l) {
    __builtin_amdgcn_global_load_lds(
        (const __attribute__((address_space(1))) unsigned int*)g,
        (__attribute__((address_space(3))) unsigned int*)l, 16, 0, 0);
}

// ---------------- A: supports = softmax(relu(emb emb^T)) -> bf16 tiled ------
__global__ __launch_bounds__(256) void k_supports(const float* __restrict__ emb,
                                                  unsigned short* __restrict__ sup) {
    const int n = blockIdx.x;
    const int t = threadIdx.x;
    __shared__ float en[E_DIM];
    __shared__ float red[4];
    if (t < E_DIM) en[t] = emb[n * E_DIM + t];
    __syncthreads();

    float sc[4];
    float mx = -1e30f;
#pragma unroll
    for (int r = 0; r < 4; ++r) {
        const float* em = &emb[(r * 256 + t) * E_DIM];
        float s = 0.f;
#pragma unroll
        for (int e = 0; e < E_DIM; ++e) s = fmaf(en[e], em[e], s);
        s = fmaxf(s, 0.f);
        sc[r] = s;
        mx = fmaxf(mx, s);
    }
#pragma unroll
    for (int o = 32; o > 0; o >>= 1) mx = fmaxf(mx, __shfl_xor(mx, o));
    if ((t & 63) == 0) red[t >> 6] = mx;
    __syncthreads();
    mx = fmaxf(fmaxf(red[0], red[1]), fmaxf(red[2], red[3]));

    float sum = 0.f;
#pragma unroll
    for (int r = 0; r < 4; ++r) { sc[r] = __expf(sc[r] - mx); sum += sc[r]; }
#pragma unroll
    for (int o = 32; o > 0; o >>= 1) sum += __shfl_xor(sum, o);
    __syncthreads();
    if ((t & 63) == 0) red[t >> 6] = sum;
    __syncthreads();
    sum = red[0] + red[1] + red[2] + red[3];
    const float inv = 1.f / sum;
    // tiled write: panel n>>7, row n&127, k = m
#pragma unroll
    for (int r = 0; r < 4; ++r) {
        const int m = r * 256 + t;
        const int off = (n >> 7) * 131072 + (m >> 6) * 8192 + ((m >> 3) & 7) * 1024
                      + (n & 127) * 8 + (m & 7);
        sup[off] = f2bf(sc[r] * inv);
    }
}

// ---------------- B: xbt tiled panels; j = b*64+c, k = m --------------------
__global__ __launch_bounds__(256) void k_xt(const float* __restrict__ x,
                                            unsigned short* __restrict__ xbt) {
    __shared__ __align__(16) unsigned short xt[64 * 72];   // [c][m], pitch 72
    const int t  = threadIdx.x;
    const int b  = blockIdx.y;
    const int m0 = blockIdx.x * 64;                        // kt = blockIdx.x
    const int c  = t & 63, mr = t >> 6;
    const float* src = x + ((long)b * N_NODES + m0 + mr) * 64 + c;
#pragma unroll
    for (int i = 0; i < 16; ++i)
        xt[c * 72 + mr + i * 4] = f2bf(src[(long)i * 4 * 64]);
    __syncthreads();
    const int cc = t >> 2, mb = (t & 3) * 16;              // 16 m per thread
    const int p  = b >> 1, jr = (b & 1) * 64 + cc;         // panel, row-in-panel
    unsigned short* dst = xbt + (long)p * 131072 + (long)blockIdx.x * 8192 + jr * 8;
    *(bf16x8*)(dst + ((t & 3) * 2 + 0) * 1024) = *(const bf16x8*)(&xt[cc * 72 + mb]);
    *(bf16x8*)(dst + ((t & 3) * 2 + 1) * 1024) = *(const bf16x8*)(&xt[cc * 72 + mb + 8]);
}

// ---------------- C: Wt per-node tiled [kblk 8][o 64][8], bias f32 ----------
__global__ __launch_bounds__(256) void k_weights(const float* __restrict__ emb,
                                                 const float* __restrict__ wpool,
                                                 const float* __restrict__ bpool,
                                                 unsigned short* __restrict__ Wt,
                                                 float* __restrict__ bias) {
    const int n = blockIdx.x;
    const int t = threadIdx.x;
    __shared__ float en[E_DIM];
    __shared__ float wl[64 * 65];   // [i][o], pitch 65
    if (t < E_DIM) en[t] = emb[n * E_DIM + t];
    __syncthreads();
#pragma unroll 4
    for (int r = 0; r < 16; ++r) {
        const int idx = r * 256 + t;    // i = idx>>6, o = idx&63
        float s = 0.f;
#pragma unroll
        for (int e = 0; e < E_DIM; ++e) s = fmaf(en[e], wpool[e * 4096 + idx], s);
        wl[(idx >> 6) * 65 + (idx & 63)] = s;
    }
    if (t < 64) {
        float s = 0.f;
#pragma unroll
        for (int e = 0; e < E_DIM; ++e) s = fmaf(en[e], bpool[e * 64 + t], s);
        bias[n * 64 + t] = s;
    }
    __syncthreads();
    // tiled write: idx -> kblk = idx>>9, o = (idx>>3)&63, e = idx&7, i = kblk*8+e
#pragma unroll 4
    for (int r = 0; r < 16; ++r) {
        const int idx = r * 256 + t;
        const int i = (idx >> 9) * 8 + (idx & 7), o = (idx >> 3) & 63;
        Wt[(long)n * 4096 + idx] = f2bf(wl[i * 65 + o]);
    }
}

// ---------------- D: xg = S @ X, 128x128, BK=64, coalesced tiled staging ----
__global__ __launch_bounds__(256, 2) void k_agg(const unsigned short* __restrict__ S,
                                                const unsigned short* __restrict__ Bt,
                                                unsigned short* __restrict__ xg) {
    __shared__ __align__(16) char lds[65536];
    const int t = threadIdx.x;
    const int lane = t & 63, wid = t >> 6;

    // bijective XCD swizzle: 512 blocks, 8 XCDs, 64 blocks per XCD chunk
    const int hw   = blockIdx.x + 8 * blockIdx.y;      // grid (8, 64)
    const int work = (hw & 7) * 64 + (hw >> 3);
    const int n0 = (work & 7) * 128, j0 = (work >> 3) * 128;
    const int wr = wid >> 1, wc = wid & 1;

    f32x16 acc[2][2];
#pragma unroll
    for (int m = 0; m < 2; ++m)
#pragma unroll
        for (int n = 0; n < 2; ++n)
#pragma unroll
            for (int r = 0; r < 16; ++r) acc[m][n][r] = 0.f;

    // 32 contiguous 1KB chunks per K-tile (16 A + 16 B); wave owns 8
    const unsigned short* pA = S  + (n0 >> 7) * 131072 + lane * 8;
    const unsigned short* pB = Bt + (j0 >> 7) * 131072 + lane * 8;
    const unsigned short* sp[8];
    int doff[8];
#pragma unroll
    for (int i = 0; i < 8; ++i) {
        const int c = wid * 8 + i;
        if (c < 16) { sp[i] = pA + c * 512;        doff[i] = c * 1024; }
        else        { sp[i] = pB + (c - 16) * 512; doff[i] = 16384 + (c - 16) * 1024; }
    }
#define STAGE(buf, kt) do {                                       \
        const int ko = (kt) * 8192;                               \
        gload_lds16(sp[0] + ko, (buf) + doff[0]);                 \
        gload_lds16(sp[1] + ko, (buf) + doff[1]);                 \
        gload_lds16(sp[2] + ko, (buf) + doff[2]);                 \
        gload_lds16(sp[3] + ko, (buf) + doff[3]);                 \
        gload_lds16(sp[4] + ko, (buf) + doff[4]);                 \
        gload_lds16(sp[5] + ko, (buf) + doff[5]);                 \
        gload_lds16(sp[6] + ko, (buf) + doff[6]);                 \
        gload_lds16(sp[7] + ko, (buf) + doff[7]);                 \
    } while (0)

    // fragment offsets: kstep s gives kblk = s*2 + (lane>>5)
    int aoff[2], boff[2];
#pragma unroll
    for (int m = 0; m < 2; ++m)
        aoff[m] = (lane >> 5) * 2048 + (wr * 64 + m * 32 + (lane & 31)) * 16;
#pragma unroll
    for (int n = 0; n < 2; ++n)
        boff[n] = 16384 + (lane >> 5) * 2048 + (wc * 64 + n * 32 + (lane & 31)) * 16;

    char* cur = lds;
    char* nxt = lds + 32768;
    STAGE(cur, 0);
    for (int kt = 0; kt < 16; ++kt) {
        if (kt + 1 < 16) {
            STAGE(nxt, kt + 1);
            asm volatile("s_waitcnt vmcnt(8)" ::: "memory");
        } else {
            asm volatile("s_waitcnt vmcnt(0)" ::: "memory");
        }
        __builtin_amdgcn_s_barrier();
        __builtin_amdgcn_sched_barrier(0);
        __builtin_amdgcn_s_setprio(1);
#pragma unroll
        for (int s = 0; s < 4; ++s) {
            bf16x8 a[2], b[2];
#pragma unroll
            for (int m = 0; m < 2; ++m) a[m] = *(const bf16x8*)(cur + s * 4096 + aoff[m]);
#pragma unroll
            for (int n = 0; n < 2; ++n) b[n] = *(const bf16x8*)(cur + s * 4096 + boff[n]);
#pragma unroll
            for (int m = 0; m < 2; ++m)
#pragma unroll
                for (int n = 0; n < 2; ++n)
                    acc[m][n] = __builtin_amdgcn_mfma_f32_32x32x16_bf16(a[m], b[n], acc[m][n], 0, 0, 0);
        }
        __builtin_amdgcn_s_setprio(0);
        __builtin_amdgcn_sched_barrier(0);
        __builtin_amdgcn_s_barrier();
        __builtin_amdgcn_sched_barrier(0);
        char* tmp = cur; cur = nxt; nxt = tmp;
    }
#undef STAGE

    // epilogue: acc -> LDS bf16 [128 row][128 col] swizzled -> tiled xg
    // C layout (32x32): col = lane&31, row = (r&3) + 8*(r>>2) + 4*(lane>>5)
    char* lb = lds;
#pragma unroll
    for (int m = 0; m < 2; ++m) {
#pragma unroll
        for (int n = 0; n < 2; ++n) {
            const int col  = wc * 64 + n * 32 + (lane & 31);
            const int rowb = wr * 64 + m * 32 + 4 * (lane >> 5);
#pragma unroll
            for (int r = 0; r < 16; ++r) {
                const int row = rowb + (r & 3) + 8 * (r >> 2);
                *(unsigned short*)(lb + row * 256 + ((col * 2) ^ ((row & 7) << 4))) =
                    f2bf(acc[m][n][r]);
            }
        }
    }
    __syncthreads();
    // xg per-node tiled: node*8192 + (i>>3)*1024 + b*8 + (i&7); j = b*64+i
#pragma unroll
    for (int i = 0; i < 8; ++i) {
        const int idx = i * 256 + t;          // 2048 granules of 16B
        const int row = idx >> 4, cc = idx & 15;
        bf16x8 v = *(const bf16x8*)(lb + row * 256 + ((cc * 16) ^ ((row & 7) << 4)));
        const long dst = (long)(n0 + row) * 8192 + (cc & 7) * 1024
                       + ((j0 >> 6) + (cc >> 3)) * 8;
        *(bf16x8*)(xg + dst) = v;
    }
}

// ---------------- E: out[b,n,o] = xg_n[b,:] @ W_n + bias_n ------------------
__global__ __launch_bounds__(256) void k_out(const unsigned short* __restrict__ xg,
                                             const unsigned short* __restrict__ Wt,
                                             const float* __restrict__ bias,
                                             float* __restrict__ out) {
    __shared__ __align__(16) char lds[24576];   // xg_n 16KB | Wt_n 8KB
    const int t = threadIdx.x, lane = t & 63, wid = t >> 6;
    const int node = blockIdx.x;
    const unsigned short* gx = xg + (long)node * 8192;
    const unsigned short* gw = Wt + (long)node * 4096;
#pragma unroll
    for (int i = 0; i < 4; ++i) {
        const int c = wid * 4 + i;            // 0..15, contiguous 1KB chunks
        gload_lds16(gx + c * 512 + lane * 8, lds + c * 1024);
    }
#pragma unroll
    for (int i = 0; i < 2; ++i) {
        const int c = wid * 2 + i;            // 0..7
        gload_lds16(gw + c * 512 + lane * 8, lds + 16384 + c * 1024);
    }
    __syncthreads();

    f32x4 acc[2][4];
#pragma unroll
    for (int m = 0; m < 2; ++m)
#pragma unroll
        for (int n = 0; n < 4; ++n) acc[m][n] = f32x4{0.f, 0.f, 0.f, 0.f};

#pragma unroll
    for (int s = 0; s < 2; ++s) {
        const int kb = s * 4 + (lane >> 4);
        bf16x8 a[2], b[4];
#pragma unroll
        for (int m = 0; m < 2; ++m)
            a[m] = *(const bf16x8*)(lds + kb * 2048 + (wid * 32 + m * 16 + (lane & 15)) * 16);
#pragma unroll
        for (int n = 0; n < 4; ++n)
            b[n] = *(const bf16x8*)(lds + 16384 + kb * 1024 + (n * 16 + (lane & 15)) * 16);
#pragma unroll
        for (int m = 0; m < 2; ++m)
#pragma unroll
            for (int n = 0; n < 4; ++n)
                acc[m][n] = __builtin_amdgcn_mfma_f32_16x16x32_bf16(a[m], b[n], acc[m][n], 0, 0, 0);
    }

#pragma unroll
    for (int n = 0; n < 4; ++n) {
        const int o = n * 16 + (lane & 15);
        const float bv = bias[node * 64 + o];
#pragma unroll
        for (int m = 0; m < 2; ++m) {
            const int b0 = wid * 32 + m * 16 + (lane >> 4) * 4;
#pragma unroll
            for (int r = 0; r < 4; ++r)
                out[(long)(b0 + r) * 65536 + node * 64 + o] = acc[m][n][r] + bv;
        }
    }
}

extern "C" void kernel_launch(void* const* d_in, const int* in_sizes, int n_in,
                              void* d_out, int out_size, void* d_ws, size_t ws_size,
                              hipStream_t stream) {
    const float* x     = (const float*)d_in[0];
    const float* emb   = (const float*)d_in[1];
    const float* wpool = (const float*)d_in[2];
    const float* bpool = (const float*)d_in[3];
    float* out = (float*)d_out;

    char* ws = (char*)d_ws;
    unsigned short* sup  = (unsigned short*)(ws);                        // 2 MiB
    unsigned short* xbt  = (unsigned short*)(ws + (2u  << 20));          // 16 MiB
    unsigned short* Wt   = (unsigned short*)(ws + (18u << 20));          // 8 MiB
    float*          bias = (float*)         (ws + (26u << 20));          // 256 KiB
    unsigned short* xg   = (unsigned short*)(ws + (27u << 20));          // 16 MiB
    (void)in_sizes; (void)n_in; (void)out_size; (void)ws_size;

    k_supports<<<dim3(N_NODES), dim3(256), 0, stream>>>(emb, sup);
    k_xt<<<dim3(16, BATCH), dim3(256), 0, stream>>>(x, xbt);
    k_weights<<<dim3(N_NODES), dim3(256), 0, stream>>>(emb, wpool, bpool, Wt, bias);
    k_agg<<<dim3(8, 64), dim3(256), 0, stream>>>(sup, xbt, xg);
    k_out<<<dim3(N_NODES), dim3(256), 0, stream>>>(xg, Wt, bias, out);
}

// Round 8
// 70.724 us; speedup vs baseline: 1.5557x; 1.0024x over previous
//
#include <hip/hip_runtime.h>

#define N_NODES 1024
#define BATCH   128
#define E_DIM   16

// Operand panel format (bf16, per 128-row x 1024-k panel, 256KB):
//   elem(row, k) at  (k>>6)*8192 + ((k>>3)&7)*1024 + row*8 + (k&7)
// K-tile kt (BK=32) = shorts [kt*4096, kt*4096+4096) = 8 contiguous 1KB chunks.

typedef __attribute__((ext_vector_type(8))) short bf16x8;
typedef __attribute__((ext_vector_type(4))) float f32x4;
typedef __attribute__((ext_vector_type(16))) float f32x16;

__device__ __forceinline__ unsigned short f2bf(float f) {
    union { float f; unsigned int u; } v; v.f = f;
    unsigned int u = v.u;
    u += 0x7FFFu + ((u >> 16) & 1u);
    return (unsigned short)(u >> 16);
}

__device__ __forceinline__ void gload_lds16(const void* g, void* l) {
    __builtin_amdgcn_global_load_lds(
        (const __attribute__((address_space(1))) unsigned int*)g,
        (__attribute__((address_space(3))) unsigned int*)l, 16, 0, 0);
}

// ---------------- A: supports = softmax(relu(emb emb^T)) -> bf16 tiled ------
__global__ __launch_bounds__(256) void k_supports(const float* __restrict__ emb,
                                                  unsigned short* __restrict__ sup) {
    const int n = blockIdx.x;
    const int t = threadIdx.x;
    __shared__ float en[E_DIM];
    __shared__ float red[4];
    if (t < E_DIM) en[t] = emb[n * E_DIM + t];
    __syncthreads();

    float sc[4];
    float mx = -1e30f;
#pragma unroll
    for (int r = 0; r < 4; ++r) {
        const float* em = &emb[(r * 256 + t) * E_DIM];
        float s = 0.f;
#pragma unroll
        for (int e = 0; e < E_DIM; ++e) s = fmaf(en[e], em[e], s);
        s = fmaxf(s, 0.f);
        sc[r] = s;
        mx = fmaxf(mx, s);
    }
#pragma unroll
    for (int o = 32; o > 0; o >>= 1) mx = fmaxf(mx, __shfl_xor(mx, o));
    if ((t & 63) == 0) red[t >> 6] = mx;
    __syncthreads();
    mx = fmaxf(fmaxf(red[0], red[1]), fmaxf(red[2], red[3]));

    float sum = 0.f;
#pragma unroll
    for (int r = 0; r < 4; ++r) { sc[r] = __expf(sc[r] - mx); sum += sc[r]; }
#pragma unroll
    for (int o = 32; o > 0; o >>= 1) sum += __shfl_xor(sum, o);
    __syncthreads();
    if ((t & 63) == 0) red[t >> 6] = sum;
    __syncthreads();
    sum = red[0] + red[1] + red[2] + red[3];
    const float inv = 1.f / sum;
#pragma unroll
    for (int r = 0; r < 4; ++r) {
        const int m = r * 256 + t;
        const int off = (n >> 7) * 131072 + (m >> 6) * 8192 + ((m >> 3) & 7) * 1024
                      + (n & 127) * 8 + (m & 7);
        sup[off] = f2bf(sc[r] * inv);
    }
}

// ---------------- B: xbt tiled panels; j = b*64+c, k = m --------------------
__global__ __launch_bounds__(256) void k_xt(const float* __restrict__ x,
                                            unsigned short* __restrict__ xbt) {
    __shared__ __align__(16) unsigned short xt[64 * 72];   // [c][m], pitch 72
    const int t  = threadIdx.x;
    const int b  = blockIdx.y;
    const int m0 = blockIdx.x * 64;                        // kt64 = blockIdx.x
    const int c  = t & 63, mr = t >> 6;
    const float* src = x + ((long)b * N_NODES + m0 + mr) * 64 + c;
#pragma unroll
    for (int i = 0; i < 16; ++i)
        xt[c * 72 + mr + i * 4] = f2bf(src[(long)i * 4 * 64]);
    __syncthreads();
    const int cc = t >> 2, mb = (t & 3) * 16;              // 16 m per thread
    const int p  = b >> 1, jr = (b & 1) * 64 + cc;         // panel, row-in-panel
    unsigned short* dst = xbt + (long)p * 131072 + (long)blockIdx.x * 8192 + jr * 8;
    *(bf16x8*)(dst + ((t & 3) * 2 + 0) * 1024) = *(const bf16x8*)(&xt[cc * 72 + mb]);
    *(bf16x8*)(dst + ((t & 3) * 2 + 1) * 1024) = *(const bf16x8*)(&xt[cc * 72 + mb + 8]);
}

// ---------------- C: Wt per-node tiled [kblk 8][o 64][8], bias f32 ----------
__global__ __launch_bounds__(256) void k_weights(const float* __restrict__ emb,
                                                 const float* __restrict__ wpool,
                                                 const float* __restrict__ bpool,
                                                 unsigned short* __restrict__ Wt,
                                                 float* __restrict__ bias) {
    const int n = blockIdx.x;
    const int t = threadIdx.x;
    __shared__ float en[E_DIM];
    __shared__ float wl[64 * 65];   // [i][o], pitch 65
    if (t < E_DIM) en[t] = emb[n * E_DIM + t];
    __syncthreads();
#pragma unroll 4
    for (int r = 0; r < 16; ++r) {
        const int idx = r * 256 + t;    // i = idx>>6, o = idx&63
        float s = 0.f;
#pragma unroll
        for (int e = 0; e < E_DIM; ++e) s = fmaf(en[e], wpool[e * 4096 + idx], s);
        wl[(idx >> 6) * 65 + (idx & 63)] = s;
    }
    if (t < 64) {
        float s = 0.f;
#pragma unroll
        for (int e = 0; e < E_DIM; ++e) s = fmaf(en[e], bpool[e * 64 + t], s);
        bias[n * 64 + t] = s;
    }
    __syncthreads();
    // tiled write: idx -> kblk = idx>>9, o = (idx>>3)&63, e = idx&7, i = kblk*8+e
#pragma unroll 4
    for (int r = 0; r < 16; ++r) {
        const int idx = r * 256 + t;
        const int i = (idx >> 9) * 8 + (idx & 7), o = (idx >> 3) & 63;
        Wt[(long)n * 4096 + idx] = f2bf(wl[i * 65 + o]);
    }
}

// ---------------- D: xg = S @ X, 128x128, BK=32, depth-2 prefetch -----------
__global__ __launch_bounds__(256, 2) void k_agg(const unsigned short* __restrict__ S,
                                                const unsigned short* __restrict__ Bt,
                                                unsigned short* __restrict__ xg) {
    __shared__ __align__(16) char lds[65536];   // 4 buffers x 16KB
    const int t = threadIdx.x;
    const int lane = t & 63, wid = t >> 6;

    // bijective XCD swizzle: 512 blocks, 8 XCDs, 64 blocks per XCD chunk
    const int hw   = blockIdx.x + 8 * blockIdx.y;      // grid (8, 64)
    const int work = (hw & 7) * 64 + (hw >> 3);
    const int n0 = (work & 7) * 128, j0 = (work >> 3) * 128;
    const int wr = wid >> 1, wc = wid & 1;

    f32x16 acc[2][2];
#pragma unroll
    for (int m = 0; m < 2; ++m)
#pragma unroll
        for (int n = 0; n < 2; ++n)
#pragma unroll
            for (int r = 0; r < 16; ++r) acc[m][n][r] = 0.f;

    // 16 contiguous 1KB chunks per K-tile (8 A + 8 B); wave owns 4
    const unsigned short* pA = S  + (n0 >> 7) * 131072 + lane * 8;
    const unsigned short* pB = Bt + (j0 >> 7) * 131072 + lane * 8;
    const unsigned short* sp[4];
    int doff[4];
#pragma unroll
    for (int i = 0; i < 4; ++i) {
        const int c = wid * 4 + i;
        if (c < 8) { sp[i] = pA + c * 512;       doff[i] = c * 1024; }
        else       { sp[i] = pB + (c - 8) * 512; doff[i] = 8192 + (c - 8) * 1024; }
    }
#define STAGE(kt) do {                                                   \
        char* buf_ = lds + ((kt) & 3) * 16384;                           \
        const int ko_ = (kt) * 4096;                                     \
        gload_lds16(sp[0] + ko_, buf_ + doff[0]);                        \
        gload_lds16(sp[1] + ko_, buf_ + doff[1]);                        \
        gload_lds16(sp[2] + ko_, buf_ + doff[2]);                        \
        gload_lds16(sp[3] + ko_, buf_ + doff[3]);                        \
    } while (0)

    // fragment offsets: kstep s (0..1) gives kblk = s*2 + (lane>>5)
    int aoff[2], boff[2];
#pragma unroll
    for (int m = 0; m < 2; ++m)
        aoff[m] = (lane >> 5) * 2048 + (wr * 64 + m * 32 + (lane & 31)) * 16;
#pragma unroll
    for (int n = 0; n < 2; ++n)
        boff[n] = 8192 + (lane >> 5) * 2048 + (wc * 64 + n * 32 + (lane & 31)) * 16;

    STAGE(0); STAGE(1);                    // 8 loads/wave in flight
    for (int kt = 0; kt < 32; ++kt) {
        if (kt < 31) asm volatile("s_waitcnt vmcnt(4)" ::: "memory");
        else         asm volatile("s_waitcnt vmcnt(0)" ::: "memory");
        __builtin_amdgcn_s_barrier();
        asm volatile("" ::: "memory");     // IR fence: no LDS access hoists above
        __builtin_amdgcn_sched_barrier(0); // MIR fence
        // buf[(kt+2)&3] was last READ at iter kt-2 -> two barriers of separation
        if (kt + 2 < 32) STAGE(kt + 2);
        const char* cur = lds + (kt & 3) * 16384;
        __builtin_amdgcn_s_setprio(1);
#pragma unroll
        for (int s = 0; s < 2; ++s) {
            bf16x8 a[2], b[2];
#pragma unroll
            for (int m = 0; m < 2; ++m) a[m] = *(const bf16x8*)(cur + s * 4096 + aoff[m]);
#pragma unroll
            for (int n = 0; n < 2; ++n) b[n] = *(const bf16x8*)(cur + s * 4096 + boff[n]);
#pragma unroll
            for (int m = 0; m < 2; ++m)
#pragma unroll
                for (int n = 0; n < 2; ++n)
                    acc[m][n] = __builtin_amdgcn_mfma_f32_32x32x16_bf16(a[m], b[n], acc[m][n], 0, 0, 0);
        }
        __builtin_amdgcn_s_setprio(0);
        asm volatile("" ::: "memory");
        __builtin_amdgcn_sched_barrier(0);
    }
#undef STAGE
    __syncthreads();   // all reads done before epilogue reuses lds

    // epilogue: acc -> LDS bf16 [128 row][128 col] swizzled -> tiled xg
    // C layout (32x32): col = lane&31, row = (r&3) + 8*(r>>2) + 4*(lane>>5)
    char* lb = lds;
#pragma unroll
    for (int m = 0; m < 2; ++m) {
#pragma unroll
        for (int n = 0; n < 2; ++n) {
            const int col  = wc * 64 + n * 32 + (lane & 31);
            const int rowb = wr * 64 + m * 32 + 4 * (lane >> 5);
#pragma unroll
            for (int r = 0; r < 16; ++r) {
                const int row = rowb + (r & 3) + 8 * (r >> 2);
                *(unsigned short*)(lb + row * 256 + ((col * 2) ^ ((row & 7) << 4))) =
                    f2bf(acc[m][n][r]);
            }
        }
    }
    __syncthreads();
    // xg per-node tiled: node*8192 + (i>>3)*1024 + b*8 + (i&7); j = b*64+i
#pragma unroll
    for (int i = 0; i < 8; ++i) {
        const int idx = i * 256 + t;          // 2048 granules of 16B
        const int row = idx >> 4, cc = idx & 15;
        bf16x8 v = *(const bf16x8*)(lb + row * 256 + ((cc * 16) ^ ((row & 7) << 4)));
        const long dst = (long)(n0 + row) * 8192 + (cc & 7) * 1024
                       + ((j0 >> 6) + (cc >> 3)) * 8;
        *(bf16x8*)(xg + dst) = v;
    }
}

// ---------------- E: out[b,n,o] = xg_n[b,:] @ W_n + bias_n ------------------
__global__ __launch_bounds__(256) void k_out(const unsigned short* __restrict__ xg,
                                             const unsigned short* __restrict__ Wt,
                                             const float* __restrict__ bias,
                                             float* __restrict__ out) {
    __shared__ __align__(16) char lds[24576];   // xg_n 16KB | Wt_n 8KB
    const int t = threadIdx.x, lane = t & 63, wid = t >> 6;
    const int node = blockIdx.x;
    const unsigned short* gx = xg + (long)node * 8192;
    const unsigned short* gw = Wt + (long)node * 4096;
#pragma unroll
    for (int i = 0; i < 4; ++i) {
        const int c = wid * 4 + i;            // 0..15, contiguous 1KB chunks
        gload_lds16(gx + c * 512 + lane * 8, lds + c * 1024);
    }
#pragma unroll
    for (int i = 0; i < 2; ++i) {
        const int c = wid * 2 + i;            // 0..7
        gload_lds16(gw + c * 512 + lane * 8, lds + 16384 + c * 1024);
    }
    __syncthreads();

    f32x4 acc[2][4];
#pragma unroll
    for (int m = 0; m < 2; ++m)
#pragma unroll
        for (int n = 0; n < 4; ++n) acc[m][n] = f32x4{0.f, 0.f, 0.f, 0.f};

#pragma unroll
    for (int s = 0; s < 2; ++s) {
        const int kb = s * 4 + (lane >> 4);
        bf16x8 a[2], b[4];
#pragma unroll
        for (int m = 0; m < 2; ++m)
            a[m] = *(const bf16x8*)(lds + kb * 2048 + (wid * 32 + m * 16 + (lane & 15)) * 16);
#pragma unroll
        for (int n = 0; n < 4; ++n)
            b[n] = *(const bf16x8*)(lds + 16384 + kb * 1024 + (n * 16 + (lane & 15)) * 16);
#pragma unroll
        for (int m = 0; m < 2; ++m)
#pragma unroll
            for (int n = 0; n < 4; ++n)
                acc[m][n] = __builtin_amdgcn_mfma_f32_16x16x32_bf16(a[m], b[n], acc[m][n], 0, 0, 0);
    }

#pragma unroll
    for (int n = 0; n < 4; ++n) {
        const int o = n * 16 + (lane & 15);
        const float bv = bias[node * 64 + o];
#pragma unroll
        for (int m = 0; m < 2; ++m) {
            const int b0 = wid * 32 + m * 16 + (lane >> 4) * 4;
#pragma unroll
            for (int r = 0; r < 4; ++r)
                out[(long)(b0 + r) * 65536 + node * 64 + o] = acc[m][n][r] + bv;
        }
    }
}

extern "C" void kernel_launch(void* const* d_in, const int* in_sizes, int n_in,
                              void* d_out, int out_size, void* d_ws, size_t ws_size,
                              hipStream_t stream) {
    const float* x     = (const float*)d_in[0];
    const float* emb   = (const float*)d_in[1];
    const float* wpool = (const float*)d_in[2];
    const float* bpool = (const float*)d_in[3];
    float* out = (float*)d_out;

    char* ws = (char*)d_ws;
    unsigned short* sup  = (unsigned short*)(ws);                        // 2 MiB
    unsigned short* xbt  = (unsigned short*)(ws + (2u  << 20));          // 16 MiB
    unsigned short* Wt   = (unsigned short*)(ws + (18u << 20));          // 8 MiB
    float*          bias = (float*)         (ws + (26u << 20));          // 256 KiB
    unsigned short* xg   = (unsigned short*)(ws + (27u << 20));          // 16 MiB
    (void)in_sizes; (void)n_in; (void)out_size; (void)ws_size;

    k_supports<<<dim3(N_NODES), dim3(256), 0, stream>>>(emb, sup);
    k_xt<<<dim3(16, BATCH), dim3(256), 0, stream>>>(x, xbt);
    k_weights<<<dim3(N_NODES), dim3(256), 0, stream>>>(emb, wpool, bpool, Wt, bias);
    k_agg<<<dim3(8, 64), dim3(256), 0, stream>>>(sup, xbt, xg);
    k_out<<<dim3(N_NODES), dim3(256), 0, stream>>>(xg, Wt, bias, out);
}